// Round 1
// baseline (2591.599 us; speedup 1.0000x reference)
//
#include <hip/hip_runtime.h>
#include <math.h>

#define B_ 32
#define T_ 128
#define IN_ 128
#define H_ 256
#define OUT_ 128

// ws layout (in floats)
#define OFF_WHHT   0          // [256][1024]  W_hhT[k][g] = W_hh[g][k]
#define OFF_WAT    262144     // [256][256]   W_AT[k][i]  = W_A[i][k]
#define OFF_WCT    327680     // [256][128]   W_CT[k][o]  = W_C[o][k]
#define OFF_WCOMBT 360448     // [128][1280]  WcombT[k][c] = c<1024 ? W_ih[c][k] : W_B[c-1024][k]
#define OFF_BIAS   524288     // [1280]       c<1024 ? b_ih+b_hh : b_B
#define OFF_XGBX   525568     // [4096][1280] xg(1024) | Bx(256) per row
#define OFF_HST    5768448    // [4096][256]  h_new states
#define WS_FLOATS  6817024    // ~26 MB

__device__ __forceinline__ float sigm_f(float x) { return 1.0f / (1.0f + __expf(-x)); }
__device__ __forceinline__ float tanh_f(float x) { return 1.0f - 2.0f / (__expf(2.0f * x) + 1.0f); }

// ---------------- pack/transpose weights ----------------
__global__ __launch_bounds__(256) void pack_kernel(
    const float* __restrict__ W_hh, const float* __restrict__ W_A,
    const float* __restrict__ W_C,  const float* __restrict__ W_ih,
    const float* __restrict__ W_B,  const float* __restrict__ b_ih,
    const float* __restrict__ b_hh, const float* __restrict__ b_B,
    float* __restrict__ ws) {
  int idx = blockIdx.x * 256 + threadIdx.x;
  if (idx < 262144) {  // W_hhT
    int k = idx >> 10, g = idx & 1023;
    ws[OFF_WHHT + idx] = W_hh[g * 256 + k];
    return;
  }
  idx -= 262144;
  if (idx < 65536) {  // W_AT
    int k = idx >> 8, i = idx & 255;
    ws[OFF_WAT + idx] = W_A[i * 256 + k];
    return;
  }
  idx -= 65536;
  if (idx < 32768) {  // W_CT
    int k = idx >> 7, o = idx & 127;
    ws[OFF_WCT + idx] = W_C[o * 256 + k];
    return;
  }
  idx -= 32768;
  if (idx < 163840) {  // WcombT
    int k = idx / 1280, c = idx - k * 1280;
    ws[OFF_WCOMBT + idx] = (c < 1024) ? W_ih[c * 128 + k] : W_B[(c - 1024) * 128 + k];
    return;
  }
  idx -= 163840;
  if (idx < 1280) {  // bias
    ws[OFF_BIAS + idx] = (idx < 1024) ? (b_ih[idx] + b_hh[idx]) : b_B[idx - 1024];
  }
}

// ---------------- xg / Bx precompute: [4096 rows][1280 cols] ----------------
__global__ __launch_bounds__(256) void xg_kernel(
    const float* __restrict__ x, const float* __restrict__ WT,
    const float* __restrict__ bias, float* __restrict__ xgBx) {
  __shared__ float xs[8 * 128];
  const int tid = threadIdx.x;
  const int rt = blockIdx.x, ct = blockIdx.y;
  ((float4*)xs)[tid] = ((const float4*)(x + rt * 1024))[tid];
  __syncthreads();
  const int r = tid >> 5, cg = tid & 31;
  const int c0 = ct * 256 + cg * 8;
  const float4* b4 = (const float4*)(bias + c0);
  float4 bA = b4[0], bB = b4[1];
  float a0 = bA.x, a1 = bA.y, a2 = bA.z, a3 = bA.w;
  float a4 = bB.x, a5 = bB.y, a6 = bB.z, a7 = bB.w;
  const float4* xr4 = (const float4*)(xs + r * 128);
#pragma unroll 4
  for (int k4 = 0; k4 < 32; ++k4) {
    float4 xv = xr4[k4];
#define STEPB(kk, comp)                                                      \
    {                                                                        \
      const float4* w = (const float4*)(WT + (k4 * 4 + kk) * 1280 + c0);     \
      float4 wA = w[0], wB = w[1];                                           \
      a0 = fmaf(wA.x, comp, a0); a1 = fmaf(wA.y, comp, a1);                  \
      a2 = fmaf(wA.z, comp, a2); a3 = fmaf(wA.w, comp, a3);                  \
      a4 = fmaf(wB.x, comp, a4); a5 = fmaf(wB.y, comp, a5);                  \
      a6 = fmaf(wB.z, comp, a6); a7 = fmaf(wB.w, comp, a7);                  \
    }
    STEPB(0, xv.x) STEPB(1, xv.y) STEPB(2, xv.z) STEPB(3, xv.w)
#undef STEPB
  }
  const int row = rt * 8 + r;
  float4* dst = (float4*)(xgBx + row * 1280 + c0);
  dst[0] = make_float4(a0, a1, a2, a3);
  dst[1] = make_float4(a4, a5, a6, a7);
}

// ---------------- persistent recurrence: 32 blocks (one per batch) ----------------
__global__ __launch_bounds__(512) void recur_kernel(
    const float* __restrict__ ts_all, const float* __restrict__ tau,
    const float* __restrict__ sigma, const float* __restrict__ W_hhT,
    const float* __restrict__ W_AT, const float* __restrict__ xgBx,
    float* __restrict__ hstate) {
  const int b = blockIdx.x;
  const int tid = threadIdx.x;
  __shared__ float h_s[256];        // LSTM hidden
  __shared__ float2 fhz_s[256];     // (tanh(hc/sigma), hc/tau)
  __shared__ float gate_s[1024];
  __shared__ float z2_s[256];
  __shared__ float partv[8][256];
  __shared__ float partu[8][256];
  __shared__ float itau_s[256];
  __shared__ float isig_s[256];
  if (tid < 256) {
    itau_s[tid] = 1.0f / tau[tid];
    isig_s[tid] = 1.0f / sigma[tid];
    h_s[tid] = 0.0f;
  }
  float c_reg = 0.0f;   // LSTM cell (owned by thread tid<256)
  float hc_reg = 0.0f;  // CfC hidden (owned by thread tid<256)
  const int ci = tid & 63;
  const int ks = tid >> 6;
  const float2* Whh2 = (const float2*)W_hhT;
  const float4* WA4 = (const float4*)W_AT;
  const float4* h4 = (const float4*)h_s;
  __syncthreads();
  for (int t = 0; t < T_; ++t) {
    const int row = b * T_ + t;
    const float ts = ts_all[row];
    // ---- LSTM matvec: thread computes gates 2*tid, 2*tid+1 ----
    float2 acc = ((const float2*)(xgBx + (long)row * 1280))[tid];
    float2 p0 = make_float2(0.f, 0.f), p1 = make_float2(0.f, 0.f);
#pragma unroll 4
    for (int k4 = 0; k4 < 64; ++k4) {
      float4 hv = h4[k4];
      float2 w0 = Whh2[(k4 * 4 + 0) * 512 + tid];
      float2 w1 = Whh2[(k4 * 4 + 1) * 512 + tid];
      float2 w2 = Whh2[(k4 * 4 + 2) * 512 + tid];
      float2 w3 = Whh2[(k4 * 4 + 3) * 512 + tid];
      p0.x = fmaf(w0.x, hv.x, fmaf(w1.x, hv.y, p0.x));
      p0.y = fmaf(w0.y, hv.x, fmaf(w1.y, hv.y, p0.y));
      p1.x = fmaf(w2.x, hv.z, fmaf(w3.x, hv.w, p1.x));
      p1.y = fmaf(w2.y, hv.z, fmaf(w3.y, hv.w, p1.y));
    }
    acc.x += p0.x + p1.x;
    acc.y += p0.y + p1.y;
    ((float2*)gate_s)[tid] = acc;
    __syncthreads();
    // ---- LSTM elementwise + CfC prep (thread j = tid < 256) ----
    float hj = 0.f, hcj = hc_reg;
    if (tid < 256) {
      float i_ = sigm_f(gate_s[tid]);
      float f_ = sigm_f(gate_s[256 + tid]);
      float g_ = tanh_f(gate_s[512 + tid]);
      float o_ = sigm_f(gate_s[768 + tid]);
      c_reg = fmaf(f_, c_reg, i_ * g_);
      hj = o_ * tanh_f(c_reg);
      h_s[tid] = hj;
      float fhj = tanh_f(hcj * isig_s[tid]);
      float zj = hcj * itau_s[tid];
      fhz_s[tid] = make_float2(fhj, zj);
    }
    __syncthreads();
    // ---- v1 = W_A @ z, u = W_A @ fh (fused pass over W_AT) ----
    {
      float4 av = make_float4(0.f, 0.f, 0.f, 0.f);
      float4 au = make_float4(0.f, 0.f, 0.f, 0.f);
      const int kbase = ks * 32;
#pragma unroll 4
      for (int k = kbase; k < kbase + 32; ++k) {
        float4 w = WA4[k * 64 + ci];
        float2 fz = fhz_s[k];
        av.x = fmaf(w.x, fz.y, av.x); av.y = fmaf(w.y, fz.y, av.y);
        av.z = fmaf(w.z, fz.y, av.z); av.w = fmaf(w.w, fz.y, av.w);
        au.x = fmaf(w.x, fz.x, au.x); au.y = fmaf(w.y, fz.x, au.y);
        au.z = fmaf(w.z, fz.x, au.z); au.w = fmaf(w.w, fz.x, au.w);
      }
      ((float4*)&partv[ks][0])[ci] = av;
      ((float4*)&partu[ks][0])[ci] = au;
    }
    __syncthreads();
    float v1j = 0.f, uj = 0.f;
    if (tid < 256) {
#pragma unroll
      for (int q = 0; q < 8; ++q) {
        v1j += partv[q][tid];
        uj += partu[q][tid];
      }
      v1j *= ts;
      z2_s[tid] = v1j * itau_s[tid];
    }
    __syncthreads();
    // ---- v2 = ts * W_A @ (v1/tau) ----
    {
      float4 av = make_float4(0.f, 0.f, 0.f, 0.f);
      const int kbase = ks * 32;
#pragma unroll 4
      for (int k = kbase; k < kbase + 32; ++k) {
        float4 w = WA4[k * 64 + ci];
        float z2 = z2_s[k];
        av.x = fmaf(w.x, z2, av.x); av.y = fmaf(w.y, z2, av.y);
        av.z = fmaf(w.z, z2, av.z); av.w = fmaf(w.w, z2, av.w);
      }
      ((float4*)&partv[ks][0])[ci] = av;
    }
    __syncthreads();
    if (tid < 256) {
      float v2j = 0.f;
#pragma unroll
      for (int q = 0; q < 8; ++q) v2j += partv[q][tid];
      v2j *= ts;
      float Bxj = xgBx[(long)row * 1280 + 1024 + tid];
      float hn = hcj + v1j + 0.5f * v2j + ts * (Bxj + uj) * itau_s[tid] + hj;
      hc_reg = hn;
      hstate[(long)row * 256 + tid] = hn;
    }
    __syncthreads();
  }
}

// ---------------- y = hstate @ W_C^T + b_C ----------------
__global__ __launch_bounds__(256) void out_kernel(
    const float* __restrict__ hstate, const float* __restrict__ WCT,
    const float* __restrict__ bC, float* __restrict__ y) {
  __shared__ float hs[16 * 256];
  const int tid = threadIdx.x;
  const long base = (long)blockIdx.x * 16 * 256;
#pragma unroll
  for (int v = 0; v < 4; ++v)
    ((float4*)hs)[tid + v * 256] = ((const float4*)(hstate + base))[tid + v * 256];
  __syncthreads();
  const int r = tid >> 4, cg = tid & 15;
  const int c0 = cg * 8;
  const float4* b4 = (const float4*)(bC + c0);
  float4 bA = b4[0], bB = b4[1];
  float a0 = bA.x, a1 = bA.y, a2 = bA.z, a3 = bA.w;
  float a4 = bB.x, a5 = bB.y, a6 = bB.z, a7 = bB.w;
  const float4* hr4 = (const float4*)(hs + r * 256);
#pragma unroll 4
  for (int k4 = 0; k4 < 64; ++k4) {
    float4 hv = hr4[k4];
#define STEPD(kk, comp)                                                     \
    {                                                                       \
      const float4* w = (const float4*)(WCT + (k4 * 4 + kk) * 128 + c0);    \
      float4 wA = w[0], wB = w[1];                                          \
      a0 = fmaf(wA.x, comp, a0); a1 = fmaf(wA.y, comp, a1);                 \
      a2 = fmaf(wA.z, comp, a2); a3 = fmaf(wA.w, comp, a3);                 \
      a4 = fmaf(wB.x, comp, a4); a5 = fmaf(wB.y, comp, a5);                 \
      a6 = fmaf(wB.z, comp, a6); a7 = fmaf(wB.w, comp, a7);                 \
    }
    STEPD(0, hv.x) STEPD(1, hv.y) STEPD(2, hv.z) STEPD(3, hv.w)
#undef STEPD
  }
  const int row = blockIdx.x * 16 + r;
  float4* dst = (float4*)(y + (long)row * 128 + c0);
  dst[0] = make_float4(a0, a1, a2, a3);
  dst[1] = make_float4(a4, a5, a6, a7);
}

extern "C" void kernel_launch(void* const* d_in, const int* in_sizes, int n_in,
                              void* d_out, int out_size, void* d_ws, size_t ws_size,
                              hipStream_t stream) {
  const float* x     = (const float*)d_in[0];
  const float* tspan = (const float*)d_in[1];
  const float* tau   = (const float*)d_in[2];
  const float* sigma = (const float*)d_in[3];
  const float* W_A   = (const float*)d_in[4];
  const float* W_B   = (const float*)d_in[5];
  const float* b_B   = (const float*)d_in[6];
  const float* W_C   = (const float*)d_in[7];
  const float* b_C   = (const float*)d_in[8];
  const float* W_ih  = (const float*)d_in[9];
  const float* W_hh  = (const float*)d_in[10];
  const float* b_ih  = (const float*)d_in[11];
  const float* b_hh  = (const float*)d_in[12];
  float* ws = (float*)d_ws;
  float* y = (float*)d_out;

  pack_kernel<<<2053, 256, 0, stream>>>(W_hh, W_A, W_C, W_ih, W_B, b_ih, b_hh, b_B, ws);
  xg_kernel<<<dim3(512, 5), 256, 0, stream>>>(x, ws + OFF_WCOMBT, ws + OFF_BIAS,
                                              ws + OFF_XGBX);
  recur_kernel<<<32, 512, 0, stream>>>(tspan, tau, sigma, ws + OFF_WHHT, ws + OFF_WAT,
                                       ws + OFF_XGBX, ws + OFF_HST);
  out_kernel<<<256, 256, 0, stream>>>(ws + OFF_HST, ws + OFF_WCT, b_C, y);
}